// Round 1
// baseline (429.973 us; speedup 1.0000x reference)
//
#include <hip/hip_runtime.h>

#define T_STEPS 256
#define B_SZ 128
#define I_SZ 1024
#define O_SZ 512

// ---------------------------------------------------------------------------
// GEMM: S[r][o] = sum_k X[r][k] * W[o][k] + bias[o]
//   M = T*B = 32768, N = O = 512, K = I = 1024
//   128x128 block tile, BK=32, 256 threads, 8x8 per thread.
// ---------------------------------------------------------------------------
#define BM 128
#define BN 128
#define BK 32
#define LDT 132   // padded row stride (floats) for transposed LDS tiles; 132*4=528 B, 16B-aligned

__global__ __launch_bounds__(256, 2) void gemm_kernel(
    const float* __restrict__ X, const float* __restrict__ W,
    const float* __restrict__ bias, float* __restrict__ S)
{
    __shared__ float As[BK][LDT];
    __shared__ float Ws[BK][LDT];

    const int tid = threadIdx.x;
    const int nb  = blockIdx.x & 3;    // 4 col blocks (N=512/BN=128)
    const int mb  = blockIdx.x >> 2;   // 256 row blocks

    // wave-local 8x8 thread layout: within each wave64, tx spans 8 values, ty spans 8 values
    // -> LDS fragment reads are broadcast-heavy / conflict-free.
    const int tx = (tid & 7) | ((tid & 128) >> 4);   // 0..15
    const int ty = (tid >> 3) & 15;                  // 0..15

    const float* Ablk = X + (size_t)mb * BM * I_SZ;
    const float* Wblk = W + (size_t)nb * BN * I_SZ;

    // staging: thread handles float4 skq (0..7) of rows srow, srow+32, srow+64, srow+96
    const int skq  = tid & 7;
    const int srow = tid >> 3;

    float acc[8][8];
#pragma unroll
    for (int i = 0; i < 8; ++i)
#pragma unroll
        for (int j = 0; j < 8; ++j) acc[i][j] = 0.f;

    for (int kt = 0; kt < I_SZ; kt += BK) {
#pragma unroll
        for (int it = 0; it < 4; ++it) {
            const int row = srow + it * 32;
            float4 a = *(const float4*)(Ablk + (size_t)row * I_SZ + kt + skq * 4);
            As[skq * 4 + 0][row] = a.x;
            As[skq * 4 + 1][row] = a.y;
            As[skq * 4 + 2][row] = a.z;
            As[skq * 4 + 3][row] = a.w;
            float4 w = *(const float4*)(Wblk + (size_t)row * I_SZ + kt + skq * 4);
            Ws[skq * 4 + 0][row] = w.x;
            Ws[skq * 4 + 1][row] = w.y;
            Ws[skq * 4 + 2][row] = w.z;
            Ws[skq * 4 + 3][row] = w.w;
        }
        __syncthreads();

#pragma unroll
        for (int kk = 0; kk < BK; ++kk) {
            float4 a0 = *(const float4*)&As[kk][ty * 8];
            float4 a1 = *(const float4*)&As[kk][ty * 8 + 4];
            float4 w0 = *(const float4*)&Ws[kk][tx * 8];
            float4 w1 = *(const float4*)&Ws[kk][tx * 8 + 4];
            float av[8] = {a0.x, a0.y, a0.z, a0.w, a1.x, a1.y, a1.z, a1.w};
            float wv[8] = {w0.x, w0.y, w0.z, w0.w, w1.x, w1.y, w1.z, w1.w};
#pragma unroll
            for (int i = 0; i < 8; ++i)
#pragma unroll
                for (int j = 0; j < 8; ++j)
                    acc[i][j] += av[i] * wv[j];
        }
        __syncthreads();
    }

    const int row0 = mb * BM + ty * 8;
    const int col0 = nb * BN + tx * 8;
    float bv[8];
#pragma unroll
    for (int j = 0; j < 8; ++j) bv[j] = bias[col0 + j];
#pragma unroll
    for (int i = 0; i < 8; ++i) {
        float4 o0 = {acc[i][0] + bv[0], acc[i][1] + bv[1], acc[i][2] + bv[2], acc[i][3] + bv[3]};
        float4 o1 = {acc[i][4] + bv[4], acc[i][5] + bv[5], acc[i][6] + bv[6], acc[i][7] + bv[7]};
        *(float4*)(S + (size_t)(row0 + i) * O_SZ + col0)     = o0;
        *(float4*)(S + (size_t)(row0 + i) * O_SZ + col0 + 4) = o1;
    }
}

// ---------------------------------------------------------------------------
// Scan: per-(b,o) sequential recurrence over t. Reads S in-place from out[],
// overwrites each element with the spike. Writes t_post at the end.
// Elementwise ops match numpy rounding exactly (contract off, true division).
// ---------------------------------------------------------------------------
__global__ __launch_bounds__(256) void scan_kernel(
    float* __restrict__ out, const float* __restrict__ wl_arr)
{
#pragma clang fp contract(off)
    const int gid = blockIdx.x * 256 + threadIdx.x;   // b*O + o, 65536 threads
    const int o   = gid & (O_SZ - 1);
    const float wl = wl_arr[o];
    const float decay_s = 0.8f;   // float(1 - 1/5)
    const float decay_m = 0.9f;   // float(1 - 1/10)

    float ep = 0.f, u = 0.f, osp = 0.f, vref = 0.f, tpost = -1.f;

    for (int t = 0; t < T_STEPS; ++t) {
        const size_t idx = (size_t)t * (B_SZ * O_SZ) + gid;
        float s = out[idx];
        float iresp = s + osp * wl;          // (dot+bias) + o*wl  (same assoc as ref)
        ep = ep * decay_s + iresp;
        u  = u * decay_m + ep / 5.0f;        // true division, matches ep / TAU_S
        if (vref > 0.f) u = 0.f;             // refractory gating (== u * (1 - (vref>0)))
        osp = (u > 1.0f) ? 1.f : 0.f;
        float v = 2.0f * osp + (vref - 1.0f);
        vref = v < 0.f ? 0.f : (v > 2.f ? 2.f : v);   // clip(.,0,2)
        float cand = osp * ((float)t + 1.0f) - 1.0f;
        tpost = cand > tpost ? cand : tpost;
        out[idx] = osp;
    }
    out[(size_t)T_STEPS * B_SZ * O_SZ + (size_t)B_SZ * I_SZ + gid] = tpost;
}

// ---------------------------------------------------------------------------
// times_pre: last spike time of x per (b,i); backward scan with early exit.
// ---------------------------------------------------------------------------
__global__ __launch_bounds__(256) void tpre_kernel(
    const float* __restrict__ x, float* __restrict__ out)
{
    const int gid = blockIdx.x * 256 + threadIdx.x;   // b*I + i, 131072 threads
    float tp = -1.f;
    for (int t = T_STEPS - 1; t >= 0; --t) {
        if (x[(size_t)t * (B_SZ * I_SZ) + gid] > 0.5f) { tp = (float)t; break; }
    }
    out[(size_t)T_STEPS * B_SZ * O_SZ + gid] = tp;
}

// ---------------------------------------------------------------------------
extern "C" void kernel_launch(void* const* d_in, const int* in_sizes, int n_in,
                              void* d_out, int out_size, void* d_ws, size_t ws_size,
                              hipStream_t stream) {
    const float* x    = (const float*)d_in[0];   // [T,B,I]
    const float* w    = (const float*)d_in[1];   // [O,I]
    const float* bias = (const float*)d_in[2];   // [O]
    const float* wl   = (const float*)d_in[3];   // [O]
    float* out = (float*)d_out;                  // [T*B*O | B*I | B*O]

    // 1) S = X @ W^T + bias  -> written into the output's [T,B,O] region
    gemm_kernel<<<dim3((32768 / BM) * (O_SZ / BN)), dim3(256), 0, stream>>>(x, w, bias, out);
    // 2) per-(b,o) temporal scan, in-place spikes + t_post
    scan_kernel<<<dim3((B_SZ * O_SZ) / 256), dim3(256), 0, stream>>>(out, wl);
    // 3) times_pre from x only
    tpre_kernel<<<dim3((B_SZ * I_SZ) / 256), dim3(256), 0, stream>>>(x, out);
}

// Round 2
// 202.062 us; speedup vs baseline: 2.1279x; 2.1279x over previous
//
#include <hip/hip_runtime.h>

#define T_STEPS 256
#define B_SZ 128
#define I_SZ 1024
#define O_SZ 512
#define M_SZ (T_STEPS * B_SZ)     // 32768

typedef short bf16x8 __attribute__((ext_vector_type(8)));
typedef float f32x16 __attribute__((ext_vector_type(16)));

#define PLANE (O_SZ * I_SZ)                 // ushorts per split plane
#define WS_NEEDED ((size_t)3 * PLANE * 2)   // 3 MB

// ---------------------------------------------------------------------------
// helpers
// ---------------------------------------------------------------------------
__device__ __forceinline__ ushort f2bf_rne(float f) {
    uint u = __float_as_uint(f);
    u += ((u >> 16) & 1u) + 0x7fffu;        // round-to-nearest-even
    return (ushort)(u >> 16);
}
__device__ __forceinline__ uint pk2(float lo, float hi) {
    // exact for x in {0,1}: truncation == RNE
    return (__float_as_uint(lo) >> 16) | (__float_as_uint(hi) & 0xffff0000u);
}
__device__ __forceinline__ void gload_lds16(const void* g, void* l) {
    typedef const void __attribute__((address_space(1))) gvt;
    typedef void __attribute__((address_space(3))) svt;
    __builtin_amdgcn_global_load_lds((gvt*)g, (svt*)l, 16, 0, 0);
}

// ---------------------------------------------------------------------------
// W split: W[n][k] fp32 -> 3 bf16 planes in MFMA-fragment order:
//   plane[p] layout [kt(32)][nsg(16)][k16(2)][lane(64)][8]
//   element (n,k): kt=k>>5, k16=(k>>4)&1, kh=(k>>3)&1, l=(n&31)|(kh<<5),
//   j=k&7, nsg=n>>5
// ---------------------------------------------------------------------------
__global__ __launch_bounds__(256) void wsplit_kernel(
    const float* __restrict__ W, ushort* __restrict__ wsp)
{
    const int t = blockIdx.x * 256 + threadIdx.x;   // 65536 threads
    const int n = t >> 7, kq = t & 127, k0 = kq * 8;
    const float* wp = W + (size_t)n * I_SZ + k0;

    uint q1[4], q2[4], q3[4];
#pragma unroll
    for (int jj = 0; jj < 4; ++jj) {
        ushort s1[2], s2[2], s3[2];
#pragma unroll
        for (int e = 0; e < 2; ++e) {
            float w0 = wp[jj * 2 + e];
            ushort a1 = f2bf_rne(w0);
            float  f1 = __uint_as_float((uint)a1 << 16);
            float  r1 = w0 - f1;
            ushort a2 = f2bf_rne(r1);
            float  f2 = __uint_as_float((uint)a2 << 16);
            float  r2 = r1 - f2;
            ushort a3 = f2bf_rne(r2);
            s1[e] = a1; s2[e] = a2; s3[e] = a3;
        }
        q1[jj] = (uint)s1[0] | ((uint)s1[1] << 16);
        q2[jj] = (uint)s2[0] | ((uint)s2[1] << 16);
        q3[jj] = (uint)s3[0] | ((uint)s3[1] << 16);
    }
    const int kt = k0 >> 5, k16 = (k0 >> 4) & 1, kh = (k0 >> 3) & 1;
    const int l = (n & 31) | (kh << 5), nsg = n >> 5;
    const size_t off = ((((size_t)kt * 16 + nsg) * 2 + k16) * 64 + l) * 8;
    *(uint4*)(wsp + off)             = make_uint4(q1[0], q1[1], q1[2], q1[3]);
    *(uint4*)(wsp + PLANE + off)     = make_uint4(q2[0], q2[1], q2[2], q2[3]);
    *(uint4*)(wsp + 2 * PLANE + off) = make_uint4(q3[0], q3[1], q3[2], q3[3]);
}

// ---------------------------------------------------------------------------
// MFMA GEMM: S[M][O] = X[M][K](binary) @ (W1+W2+W3)^T + bias
//   128x256 tile, BK=32, 4 waves (2m x 2n), per-wave 64x128,
//   mfma_f32_32x32x16_bf16, 3 split planes accumulated into same acc.
// ---------------------------------------------------------------------------
__global__ __launch_bounds__(256, 2) void gemm_mfma(
    const float* __restrict__ X, const ushort* __restrict__ wsp,
    const float* __restrict__ bias, float* __restrict__ S)
{
    __shared__ uint lds_u[14336];   // A: [0,2048) uints (8KB), B: [2048,14336) (48KB)

    const int tid  = threadIdx.x;
    const int lane = tid & 63;
    const int w    = tid >> 6;
    const int wm   = w >> 1, wn = w & 1;

    // bijective XCD swizzle: 512 wgs, 8 XCDs, 64 per XCD
    const int bid     = blockIdx.x;
    const int logical = (bid & 7) * 64 + (bid >> 3);
    const int mb = logical >> 1, nb = logical & 1;
    const int row0 = mb * 128;

    // ---- A staging setup: thread handles fragment-lanes f0=2*tid, f0+1
    const int f0   = tid * 2;
    const int msub = f0 >> 7, k16s = (f0 >> 6) & 1, l0 = f0 & 63;
    const int m0   = msub * 32 + (l0 & 31);
    const int ks   = (l0 >> 5) * 8;
    const float* pa = X + (size_t)(row0 + m0) * I_SZ + k16s * 16 + ks;
    uint* adst = lds_u + f0 * 4;

    // ---- B staging setup: 12 x 1KB chunks per wave per K-step
    uint bsrc_p[12];   // plane offset (ushorts)
    uint bsrc_o[12];   // static within-plane offset (ushorts)
    const int c0 = w * 12;
#pragma unroll
    for (int i = 0; i < 12; ++i) {
        const int c = c0 + i, p = c >> 4, r = c & 15;
        bsrc_p[i] = (uint)p * PLANE;
        bsrc_o[i] = ((((uint)(nb * 8 + (r >> 1))) * 2 + (r & 1)) * 64 + lane) * 8;
    }

    f32x16 acc[2][4];
#pragma unroll
    for (int i = 0; i < 2; ++i)
#pragma unroll
        for (int j = 0; j < 4; ++j)
#pragma unroll
            for (int r = 0; r < 16; ++r) acc[i][j][r] = 0.f;

    for (int kt = 0; kt < 32; ++kt) {
        // A: load 2 rows x 8 fp32, pack to bf16 (exact), ds_write fragment order
        const float* p0 = pa + kt * 32;
        float4 a0 = *(const float4*)p0;
        float4 a1 = *(const float4*)(p0 + 4);
        float4 a2 = *(const float4*)(p0 + I_SZ);
        float4 a3 = *(const float4*)(p0 + I_SZ + 4);
        *(uint4*)adst       = make_uint4(pk2(a0.x, a0.y), pk2(a0.z, a0.w),
                                         pk2(a1.x, a1.y), pk2(a1.z, a1.w));
        *(uint4*)(adst + 4) = make_uint4(pk2(a2.x, a2.y), pk2(a2.z, a2.w),
                                         pk2(a3.x, a3.y), pk2(a3.z, a3.w));
        // B: async global->LDS, linear dest, fragment-order source
#pragma unroll
        for (int i = 0; i < 12; ++i) {
            const ushort* g = wsp + bsrc_p[i] + bsrc_o[i] + (uint)kt * 16384;
            gload_lds16(g, lds_u + 2048 + (c0 + i) * 256);
        }
        __syncthreads();

        const uint* Au = lds_u;
        const uint* Bu = lds_u + 2048;
#pragma unroll
        for (int k16 = 0; k16 < 2; ++k16) {
            bf16x8 af0 = *(const bf16x8*)(Au + ((wm * 2 + 0) * 2 + k16) * 256 + lane * 4);
            bf16x8 af1 = *(const bf16x8*)(Au + ((wm * 2 + 1) * 2 + k16) * 256 + lane * 4);
#pragma unroll
            for (int p = 0; p < 3; ++p) {
#pragma unroll
                for (int sn = 0; sn < 4; ++sn) {
                    bf16x8 bf = *(const bf16x8*)(Bu + (p * 16 + (wn * 4 + sn) * 2 + k16) * 256 + lane * 4);
                    acc[0][sn] = __builtin_amdgcn_mfma_f32_32x32x16_bf16(af0, bf, acc[0][sn], 0, 0, 0);
                    acc[1][sn] = __builtin_amdgcn_mfma_f32_32x32x16_bf16(af1, bf, acc[1][sn], 0, 0, 0);
                }
            }
        }
        __syncthreads();
    }

    // epilogue: D row=(reg&3)+8*(reg>>2)+4*(lane>>5), col=lane&31 (from B operand)
    const int colb = nb * 256 + wn * 128 + (lane & 31);
    const int rowb = row0 + wm * 64 + 4 * (lane >> 5);
    float bv[4];
#pragma unroll
    for (int sn = 0; sn < 4; ++sn) bv[sn] = bias[colb + sn * 32];
#pragma unroll
    for (int sm = 0; sm < 2; ++sm)
#pragma unroll
        for (int sn = 0; sn < 4; ++sn)
#pragma unroll
            for (int r = 0; r < 16; ++r) {
                const int rr = rowb + sm * 32 + (r & 3) + 8 * (r >> 2);
                S[(size_t)rr * O_SZ + colb + sn * 32] = acc[sm][sn][r] + bv[sn];
            }
}

// ---------------------------------------------------------------------------
// Fallback fp32 GEMM (round-1 kernel) if ws is too small for split planes.
// ---------------------------------------------------------------------------
#define BM 128
#define BN 128
#define BK 32
#define LDT 132

__global__ __launch_bounds__(256, 2) void gemm_fp32(
    const float* __restrict__ X, const float* __restrict__ W,
    const float* __restrict__ bias, float* __restrict__ S)
{
    __shared__ float As[BK][LDT];
    __shared__ float Ws[BK][LDT];
    const int tid = threadIdx.x;
    const int nb = blockIdx.x & 3;
    const int mb = blockIdx.x >> 2;
    const int tx = (tid & 7) | ((tid & 128) >> 4);
    const int ty = (tid >> 3) & 15;
    const float* Ablk = X + (size_t)mb * BM * I_SZ;
    const float* Wblk = W + (size_t)nb * BN * I_SZ;
    const int skq = tid & 7;
    const int srow = tid >> 3;
    float acc[8][8];
#pragma unroll
    for (int i = 0; i < 8; ++i)
#pragma unroll
        for (int j = 0; j < 8; ++j) acc[i][j] = 0.f;
    for (int kt = 0; kt < I_SZ; kt += BK) {
#pragma unroll
        for (int it = 0; it < 4; ++it) {
            const int row = srow + it * 32;
            float4 a = *(const float4*)(Ablk + (size_t)row * I_SZ + kt + skq * 4);
            As[skq * 4 + 0][row] = a.x; As[skq * 4 + 1][row] = a.y;
            As[skq * 4 + 2][row] = a.z; As[skq * 4 + 3][row] = a.w;
            float4 wv = *(const float4*)(Wblk + (size_t)row * I_SZ + kt + skq * 4);
            Ws[skq * 4 + 0][row] = wv.x; Ws[skq * 4 + 1][row] = wv.y;
            Ws[skq * 4 + 2][row] = wv.z; Ws[skq * 4 + 3][row] = wv.w;
        }
        __syncthreads();
#pragma unroll
        for (int kk = 0; kk < BK; ++kk) {
            float4 a0 = *(const float4*)&As[kk][ty * 8];
            float4 a1 = *(const float4*)&As[kk][ty * 8 + 4];
            float4 w0 = *(const float4*)&Ws[kk][tx * 8];
            float4 w1 = *(const float4*)&Ws[kk][tx * 8 + 4];
            float av[8] = {a0.x, a0.y, a0.z, a0.w, a1.x, a1.y, a1.z, a1.w};
            float wv[8] = {w0.x, w0.y, w0.z, w0.w, w1.x, w1.y, w1.z, w1.w};
#pragma unroll
            for (int i = 0; i < 8; ++i)
#pragma unroll
                for (int j = 0; j < 8; ++j) acc[i][j] += av[i] * wv[j];
        }
        __syncthreads();
    }
    const int row0 = mb * BM + ty * 8;
    const int col0 = nb * BN + tx * 8;
    float bv[8];
#pragma unroll
    for (int j = 0; j < 8; ++j) bv[j] = bias[col0 + j];
#pragma unroll
    for (int i = 0; i < 8; ++i) {
        float4 o0 = {acc[i][0] + bv[0], acc[i][1] + bv[1], acc[i][2] + bv[2], acc[i][3] + bv[3]};
        float4 o1 = {acc[i][4] + bv[4], acc[i][5] + bv[5], acc[i][6] + bv[6], acc[i][7] + bv[7]};
        *(float4*)(S + (size_t)(row0 + i) * O_SZ + col0)     = o0;
        *(float4*)(S + (size_t)(row0 + i) * O_SZ + col0 + 4) = o1;
    }
}

// ---------------------------------------------------------------------------
// Scan: per-(b,o) sequential recurrence over t (exact elementwise semantics).
// ---------------------------------------------------------------------------
__global__ __launch_bounds__(256) void scan_kernel(
    float* __restrict__ out, const float* __restrict__ wl_arr)
{
#pragma clang fp contract(off)
    const int gid = blockIdx.x * 256 + threadIdx.x;
    const int o   = gid & (O_SZ - 1);
    const float wl = wl_arr[o];
    const float decay_s = 0.8f;
    const float decay_m = 0.9f;
    float ep = 0.f, u = 0.f, osp = 0.f, vref = 0.f, tpost = -1.f;
    for (int t = 0; t < T_STEPS; ++t) {
        const size_t idx = (size_t)t * (B_SZ * O_SZ) + gid;
        float s = out[idx];
        float iresp = s + osp * wl;
        ep = ep * decay_s + iresp;
        u  = u * decay_m + ep / 5.0f;
        if (vref > 0.f) u = 0.f;
        osp = (u > 1.0f) ? 1.f : 0.f;
        float v = 2.0f * osp + (vref - 1.0f);
        vref = v < 0.f ? 0.f : (v > 2.f ? 2.f : v);
        float cand = osp * ((float)t + 1.0f) - 1.0f;
        tpost = cand > tpost ? cand : tpost;
        out[idx] = osp;
    }
    out[(size_t)T_STEPS * B_SZ * O_SZ + (size_t)B_SZ * I_SZ + gid] = tpost;
}

// ---------------------------------------------------------------------------
// times_pre
// ---------------------------------------------------------------------------
__global__ __launch_bounds__(256) void tpre_kernel(
    const float* __restrict__ x, float* __restrict__ out)
{
    const int gid = blockIdx.x * 256 + threadIdx.x;
    float tp = -1.f;
    for (int t = T_STEPS - 1; t >= 0; --t) {
        if (x[(size_t)t * (B_SZ * I_SZ) + gid] > 0.5f) { tp = (float)t; break; }
    }
    out[(size_t)T_STEPS * B_SZ * O_SZ + gid] = tp;
}

// ---------------------------------------------------------------------------
extern "C" void kernel_launch(void* const* d_in, const int* in_sizes, int n_in,
                              void* d_out, int out_size, void* d_ws, size_t ws_size,
                              hipStream_t stream) {
    const float* x    = (const float*)d_in[0];
    const float* w    = (const float*)d_in[1];
    const float* bias = (const float*)d_in[2];
    const float* wl   = (const float*)d_in[3];
    float* out = (float*)d_out;

    if (ws_size >= WS_NEEDED) {
        ushort* wsp = (ushort*)d_ws;
        wsplit_kernel<<<dim3(256), dim3(256), 0, stream>>>(w, wsp);
        gemm_mfma<<<dim3(512), dim3(256), 0, stream>>>(x, wsp, bias, out);
    } else {
        gemm_fp32<<<dim3(1024), dim3(256), 0, stream>>>(x, w, bias, out);
    }
    scan_kernel<<<dim3((B_SZ * O_SZ) / 256), dim3(256), 0, stream>>>(out, wl);
    tpre_kernel<<<dim3((B_SZ * I_SZ) / 256), dim3(256), 0, stream>>>(x, out);
}